// Round 3
// baseline (7143.130 us; speedup 1.0000x reference)
//
#include <hip/hip_runtime.h>
#include <hip/hip_fp16.h>
#include <stdint.h>
#include <stddef.h>

// DRNN (dilated 3-layer LSTM), B=128, T=1024, F=128, H=256, dil=[1,2,4].
//  - Input GEMMs hoisted out of recurrence (f16 MFMA 16x16x32), G in 67MB chunks.
//  - R6 (fixes R5's measured stalls: W remat -> L2 restream [VGPR=96<128],
//    vmcnt(0) drain at __syncthreads exposing G HBM latency, poll RTT exposed,
//    8-bank hbuf conflicts [2.1M]):
//      * W B-frags pinned in VGPRs via asm "+v" (not rematerializable).
//      * Raw s_barrier + lgkmcnt(0) (no vmcnt drain): G prefetch stays in
//        flight across barriers (T4 counted-vmcnt discipline).
//      * 2 batch-groups per WG (16 batches) sharing pinned W; group B's
//        compute hides group A's exchange RTT. Grid 16x512, pair = blk^8.
//      * hbuf [16][256] f16 with 16B-chunk XOR swizzle (ch ^= row&7):
//        perfect bank spread for A-frag ds_read_b128 + conflict-free writes.
//  - Exchange protocol unchanged from verified R3/R5: tagged words
//    {tag=t+1 | f16x2}, parity t&1, relaxed agent atomics, same-XCD pair.

typedef _Float16 f16;
typedef _Float16 v2h __attribute__((ext_vector_type(2)));
typedef _Float16 v8h __attribute__((ext_vector_type(8)));
typedef __fp16 h2_raw __attribute__((ext_vector_type(2)));
typedef __fp16 h8_raw __attribute__((ext_vector_type(8)));
typedef float v4f __attribute__((ext_vector_type(4)));
typedef unsigned long long u64;

#define DEVINL static __device__ __forceinline__

DEVINL float sigm(float x) { return 1.0f / (1.0f + __expf(-x)); }
DEVINL float tanh_(float x) {
  x = fminf(fmaxf(x, -15.0f), 15.0f);
  float e = __expf(-2.0f * x);
  return (1.0f - e) / (1.0f + e);
}
DEVINL v2h pack2(float a, float b) {
  return __builtin_bit_cast(v2h, __builtin_amdgcn_cvt_pkrtz(a, b));
}
DEVINL v4f mfma_16x16x32(v8h a, v8h b, v4f c) {
  return __builtin_amdgcn_mfma_f32_16x16x32_f16(__builtin_bit_cast(h8_raw, a),
                                                __builtin_bit_cast(h8_raw, b), c,
                                                0, 0, 0);
}

// Workgroup barrier WITHOUT vmcnt drain: LDS ordered (lgkmcnt(0)), global
// loads/stores stay in flight (compiler inserts counted vmcnt at use).
DEVINL void wg_barrier() {
  __builtin_amdgcn_sched_barrier(0);
  asm volatile("s_waitcnt lgkmcnt(0)" ::: "memory");
  __builtin_amdgcn_s_barrier();
  asm volatile("" ::: "memory");
  __builtin_amdgcn_sched_barrier(0);
}

// hbuf is [16 rows][256 f16] with 16B-chunk swizzle: chunk' = chunk ^ (row&7).
DEVINL uint32_t* hb_word(f16 (*hb)[256], int row, int wd) {  // wd = dim/2, 0..127
  int ch = (wd >> 2) ^ (row & 7);
  return (uint32_t*)((char*)hb + row * 512 + ch * 16 + (wd & 3) * 4);
}
DEVINL v8h hb_frag(const f16 (*hb)[256], int row, int kt, int s4) {
  int ch = (kt * 4 + s4) ^ (row & 7);
  return *(const v8h*)((const char*)hb + row * 512 + ch * 16);
}

// ---------------- prep ----------------

__global__ void k_cvt_x(const float2* __restrict__ src, v2h* __restrict__ dst, int n2) {
  int i = blockIdx.x * blockDim.x + threadIdx.x;
  int st = gridDim.x * blockDim.x;
  for (; i < n2; i += st) {
    float2 v = src[i];
    dst[i] = pack2(v.x, v.y);
  }
}

__global__ void k_prep_w(const float* __restrict__ wih0, const float* __restrict__ whh0,
                         const float* __restrict__ wih1, const float* __restrict__ whh1,
                         const float* __restrict__ wih2, const float* __restrict__ whh2,
                         const float* __restrict__ bi0, const float* __restrict__ bh0,
                         const float* __restrict__ bi1, const float* __restrict__ bh1,
                         const float* __restrict__ bi2, const float* __restrict__ bh2,
                         f16* wih0f, f16* whh0f, f16* wih1f, f16* whh1f,
                         f16* wih2f, f16* whh2f,
                         float* bias0, float* bias1, float* bias2) {
  int i = blockIdx.x * blockDim.x + threadIdx.x;  // grid covers 262144
  if (i < 131072) wih0f[i] = (f16)wih0[i];
  whh0f[i] = (f16)whh0[i];
  wih1f[i] = (f16)wih1[i];
  whh1f[i] = (f16)whh1[i];
  wih2f[i] = (f16)wih2[i];
  whh2f[i] = (f16)whh2[i];
  if (i < 1024) {
    bias0[i] = bi0[i] + bh0[i];
    bias1[i] = bi1[i] + bh1[i];
    bias2[i] = bi2[i] + bh2[i];
  }
}

// ---------------- input GEMM (not the current bottleneck; unchanged) ----------------

template <int K>
__launch_bounds__(256)
__global__ void k_gemm(const f16* __restrict__ A, int Tb, int t0,
                       const f16* __restrict__ W, const float* __restrict__ bias,
                       f16* __restrict__ G) {
  constexpr int LDK = K + 8;
  __shared__ f16 As[64 * LDK];
  int b = blockIdx.x >> 2, tb = blockIdx.x & 3;
  const f16* Ablk = A + ((size_t)b * Tb + t0 + tb * 64) * K;
  int tid = threadIdx.x;

  constexpr int NV = 64 * K / 8;
  const uint4* src = (const uint4*)Ablk;
  for (int i = tid; i < NV; i += 256) {
    int e = i * 8;
    int r = e / K, c0 = e % K;
    *(uint4*)&As[r * LDK + c0] = src[i];
  }
  __syncthreads();

  int wave = tid >> 6, lane = tid & 63;
  int lm = lane & 15, lk = (lane >> 4) * 8;

  v8h af[K / 32];
#pragma unroll
  for (int kc = 0; kc < K / 32; ++kc)
    af[kc] = *(const v8h*)&As[(wave * 16 + lm) * LDK + kc * 32 + lk];

  size_t grow0 = (size_t)b * 256 + tb * 64 + wave * 16;
  for (int nt = 0; nt < 64; ++nt) {
    v4f acc = {0.0f, 0.0f, 0.0f, 0.0f};
    const f16* Wrow = W + (size_t)(nt * 16 + lm) * K + lk;
#pragma unroll
    for (int kc = 0; kc < K / 32; ++kc) {
      v8h bf = *(const v8h*)(Wrow + kc * 32);
      acc = mfma_16x16x32(af[kc], bf, acc);
    }
    float bv = bias[nt * 16 + lm];
#pragma unroll
    for (int r = 0; r < 4; ++r) {
      int m = (lane >> 4) * 4 + r;
      G[(grow0 + m) * 1024 + nt * 16 + lm] = (f16)(acc[r] + bv);
    }
  }
}

// ---------------- recurrence (R6: 2 groups/WG, pinned W, raw barriers) ----------------
// grid 16 x 512. pr=blk&7 -> groups g0=2pr, g1=2pr+1 (8 batches each);
// half=blk>>3 -> dims [half*128, half*128+128) of all 4 gates. Partner blk^8.
// Wave wv: gate q=wv&3, colsub cs=wv>>2; per group 4 N-tiles x 8 K-tiles = 32
// MFMA; W B-frags pinned in 128 VGPRs, shared by both groups.
// Per step: P1 {MFMA A, MFMA B, gq stores, G prefetch} BAR1
//           P2 {poll issue, cell A, publish A, cell B, publish B, outputs,
//               spin+partner hbuf writes} BAR2.

#define LSTM_CELL(gq, gv, c0v, c1v, h0v, h1v)                                 \
  {                                                                           \
    float2 zi = *(const float2*)&gq[0][bl][2 * p];                            \
    float2 zf = *(const float2*)&gq[1][bl][2 * p];                            \
    float2 zg = *(const float2*)&gq[2][bl][2 * p];                            \
    float2 zo = *(const float2*)&gq[3][bl][2 * p];                            \
    v2h G0 = __builtin_bit_cast(v2h, gv[0]);                                  \
    v2h G1 = __builtin_bit_cast(v2h, gv[1]);                                  \
    v2h G2 = __builtin_bit_cast(v2h, gv[2]);                                  \
    v2h G3 = __builtin_bit_cast(v2h, gv[3]);                                  \
    float i0 = sigm(zi.x + (float)G0[0]), i1 = sigm(zi.y + (float)G0[1]);     \
    float f0 = sigm(zf.x + (float)G1[0]), f1 = sigm(zf.y + (float)G1[1]);     \
    float g0v = tanh_(zg.x + (float)G2[0]), g1v = tanh_(zg.y + (float)G2[1]); \
    float o0 = sigm(zo.x + (float)G3[0]), o1 = sigm(zo.y + (float)G3[1]);     \
    c0v = f0 * c0v + i0 * g0v;                                                \
    c1v = f1 * c1v + i1 * g1v;                                                \
    h0v = o0 * tanh_(c0v);                                                    \
    h1v = o1 * tanh_(c1v);                                                    \
  }

template <int LAYER>
__launch_bounds__(512, 2)
__global__ void k_rec(const f16* __restrict__ G,   // chunk [128][256][1024] f16
                      const f16* __restrict__ Whh, // [1024][256] f16
                      int t0, int steps,
                      f16* __restrict__ Hout, float* __restrict__ y,
                      float* __restrict__ hstate, float* __restrict__ cstate,
                      u64* hxw) {
  int blk = blockIdx.x;                 // 0..15
  int pr = blk & 7, half = blk >> 3;    // partner = blk ^ 8 (same XCD)
  int g0 = pr * 2, g1 = pr * 2 + 1;
  int tid = threadIdx.x;
  int lane = tid & 63;
  int wv = tid >> 6;

  // MFMA roles
  int q = wv & 3, cs = wv >> 2;
  int colbase = q * 256 + half * 128 + cs * 64;
  int arow = lane & 15, s4 = lane >> 4, kq = s4 * 8;

  // cell identity: thread = (batch-in-group bl, dim-pair p)
  int bl = wv, p = lane;
  int bA = g0 * 8 + bl, bB = g1 * 8 + bl;

  __shared__ __align__(16) f16 hbA[16][256], hbB[16][256];  // swizzled
  __shared__ float gqA[4][8][132], gqB[4][8][132];

  // W_hh B-fragments, pinned: lane holds W[colbase+nt*16+arow][kt*32+kq+j]
  v8h wf[32];
#pragma unroll
  for (int nt = 0; nt < 4; ++nt)
#pragma unroll
    for (int kt = 0; kt < 8; ++kt)
      wf[nt * 8 + kt] =
          *(const v8h*)&Whh[(size_t)(colbase + nt * 16 + arow) * 256 + kt * 32 + kq];
#pragma unroll
  for (int i = 0; i < 32; ++i)
    asm volatile("" : "+v"(wf[i]));  // opaque: cannot be rematerialized/reloaded

  // zero hbufs (rows 8-15 stay zero; MFMA rows 8-15 discarded)
  {
    uint32_t* z0 = (uint32_t*)&hbA[0][0];
    uint32_t* z1 = (uint32_t*)&hbB[0][0];
    for (int i = tid; i < 2048; i += 512) { z0[i] = 0u; z1[i] = 0u; }
  }
  __syncthreads();

  float cA0 = 0.f, cA1 = 0.f, hA0 = 0.f, hA1 = 0.f;
  float cB0 = 0.f, cB1 = 0.f, hB0 = 0.f, hB1 = 0.f;
  if (t0 > 0) {  // restore h (both halves) and own c, both groups
    for (int w = tid; w < 1024; w += 512) {
      int rb = w >> 7, kp = w & 127;
      float2 ha = *(const float2*)&hstate[(size_t)(g0 * 8 + rb) * 256 + 2 * kp];
      *hb_word(hbA, rb, kp) = __builtin_bit_cast(uint32_t, pack2(ha.x, ha.y));
      float2 hb = *(const float2*)&hstate[(size_t)(g1 * 8 + rb) * 256 + 2 * kp];
      *hb_word(hbB, rb, kp) = __builtin_bit_cast(uint32_t, pack2(hb.x, hb.y));
    }
    float2 ca = *(const float2*)&cstate[(size_t)bA * 256 + half * 128 + 2 * p];
    cA0 = ca.x; cA1 = ca.y;
    float2 cb = *(const float2*)&cstate[(size_t)bB * 256 + half * 128 + 2 * p];
    cB0 = cb.x; cB1 = cb.y;
  }
  __syncthreads();

  u64* pubA = hxw + (size_t)(g0 * 2 + half) * 1024;
  const u64* pwA = hxw + (size_t)(g0 * 2 + (1 - half)) * 1024;
  u64* pubB = hxw + (size_t)(g1 * 2 + half) * 1024;
  const u64* pwB = hxw + (size_t)(g1 * 2 + (1 - half)) * 1024;

  const f16* GcA = G + (size_t)bA * 256 * 1024 + half * 128 + 2 * p;
  const f16* GcB = G + (size_t)bB * 256 * 1024 + half * 128 + 2 * p;
  uint32_t gvA[4], gvB[4], gnA[4], gnB[4];
#pragma unroll
  for (int j = 0; j < 4; ++j) {
    gvA[j] = *(const uint32_t*)&GcA[j * 256];
    gvB[j] = *(const uint32_t*)&GcB[j * 256];
  }

  for (int s = 0; s < steps; ++s) {
    int t = t0 + s;
    int par = t & 1;

    // ---- P1: MFMA both groups (B-frags pinned; A-frags from swizzled LDS) ----
    {
      v4f acc[4] = {{0.f, 0.f, 0.f, 0.f}, {0.f, 0.f, 0.f, 0.f},
                    {0.f, 0.f, 0.f, 0.f}, {0.f, 0.f, 0.f, 0.f}};
#pragma unroll
      for (int kt = 0; kt < 8; ++kt) {
        v8h a = hb_frag(hbA, arow, kt, s4);
#pragma unroll
        for (int nt = 0; nt < 4; ++nt)
          acc[nt] = mfma_16x16x32(a, wf[nt * 8 + kt], acc[nt]);
      }
      if (lane < 32) {
        int r0 = (lane >> 4) * 4, d0 = cs * 64 + (lane & 15);
#pragma unroll
        for (int nt = 0; nt < 4; ++nt)
#pragma unroll
          for (int r = 0; r < 4; ++r)
            gqA[q][r0 + r][d0 + nt * 16] = acc[nt][r];
      }
    }
    {
      v4f acc[4] = {{0.f, 0.f, 0.f, 0.f}, {0.f, 0.f, 0.f, 0.f},
                    {0.f, 0.f, 0.f, 0.f}, {0.f, 0.f, 0.f, 0.f}};
#pragma unroll
      for (int kt = 0; kt < 8; ++kt) {
        v8h a = hb_frag(hbB, arow, kt, s4);
#pragma unroll
        for (int nt = 0; nt < 4; ++nt)
          acc[nt] = mfma_16x16x32(a, wf[nt * 8 + kt], acc[nt]);
      }
      if (lane < 32) {
        int r0 = (lane >> 4) * 4, d0 = cs * 64 + (lane & 15);
#pragma unroll
        for (int nt = 0; nt < 4; ++nt)
#pragma unroll
          for (int r = 0; r < 4; ++r)
            gqB[q][r0 + r][d0 + nt * 16] = acc[nt][r];
      }
    }
    // G prefetch for t+1 (stays in flight across the raw barriers)
    if (s + 1 < steps) {
#pragma unroll
      for (int j = 0; j < 4; ++j) {
        gnA[j] = *(const uint32_t*)&GcA[(size_t)(s + 1) * 1024 + j * 256];
        gnB[j] = *(const uint32_t*)&GcB[(size_t)(s + 1) * 1024 + j * 256];
      }
    }
    wg_barrier();  // BAR1 (no vmcnt drain)

    // ---- P2: cells + exchange ----
    const u64* ppA = &pwA[(size_t)par * 512 + bl * 64 + p];
    const u64* ppB = &pwB[(size_t)par * 512 + bl * 64 + p];
    u64 wpA = __hip_atomic_load(ppA, __ATOMIC_RELAXED, __HIP_MEMORY_SCOPE_AGENT);
    u64 wpB = __hip_atomic_load(ppB, __ATOMIC_RELAXED, __HIP_MEMORY_SCOPE_AGENT);

    LSTM_CELL(gqA, gvA, cA0, cA1, hA0, hA1);
    uint32_t hpA = __builtin_bit_cast(uint32_t, pack2(hA0, hA1));
    __hip_atomic_store(&pubA[(size_t)par * 512 + bl * 64 + p],
                       ((u64)(uint32_t)(t + 1) << 32) | (u64)hpA,
                       __ATOMIC_RELAXED, __HIP_MEMORY_SCOPE_AGENT);
    *hb_word(hbA, bl, half * 64 + p) = hpA;

    LSTM_CELL(gqB, gvB, cB0, cB1, hB0, hB1);
    uint32_t hpB = __builtin_bit_cast(uint32_t, pack2(hB0, hB1));
    __hip_atomic_store(&pubB[(size_t)par * 512 + bl * 64 + p],
                       ((u64)(uint32_t)(t + 1) << 32) | (u64)hpB,
                       __ATOMIC_RELAXED, __HIP_MEMORY_SCOPE_AGENT);
    *hb_word(hbB, bl, half * 64 + p) = hpB;

    // outputs (fire-and-forget; overlap the poll wait)
    if (LAYER == 0) {
      if ((t & 1) == 0) {
        v2h hr;
        hr[0] = (f16)hA0; hr[1] = (f16)hA1;
        *(uint32_t*)&Hout[((size_t)bA * 512 + (t >> 1)) * 256 + half * 128 + 2 * p] =
            __builtin_bit_cast(uint32_t, hr);
        hr[0] = (f16)hB0; hr[1] = (f16)hB1;
        *(uint32_t*)&Hout[((size_t)bB * 512 + (t >> 1)) * 256 + half * 128 + 2 * p] =
            __builtin_bit_cast(uint32_t, hr);
      }
    } else if (LAYER == 1) {
      if ((t & 1) == 0) {
        v2h hr;
        hr[0] = (f16)hA0; hr[1] = (f16)hA1;
        *(uint32_t*)&Hout[((size_t)bA * 256 + (t >> 1)) * 256 + half * 128 + 2 * p] =
            __builtin_bit_cast(uint32_t, hr);
        hr[0] = (f16)hB0; hr[1] = (f16)hB1;
        *(uint32_t*)&Hout[((size_t)bB * 256 + (t >> 1)) * 256 + half * 128 + 2 * p] =
            __builtin_bit_cast(uint32_t, hr);
      }
    } else {
      size_t baseA = ((size_t)bA * 1024 + (size_t)t * 4) * 256 + half * 128 + 2 * p;
      float2 hvA; hvA.x = hA0; hvA.y = hA1;
      *(float2*)&y[baseA] = hvA;
      *(float2*)&y[baseA + 256] = hvA;
      *(float2*)&y[baseA + 512] = hvA;
      *(float2*)&y[baseA + 768] = hvA;
      size_t baseB = ((size_t)bB * 1024 + (size_t)t * 4) * 256 + half * 128 + 2 * p;
      float2 hvB; hvB.x = hB0; hvB.y = hB1;
      *(float2*)&y[baseB] = hvB;
      *(float2*)&y[baseB + 256] = hvB;
      *(float2*)&y[baseB + 512] = hvB;
      *(float2*)&y[baseB + 768] = hvB;
    }

    if (s + 1 < steps) {  // partner halves of h_t for next step
      while ((int)(wpA >> 32) < t + 1)
        wpA = __hip_atomic_load(ppA, __ATOMIC_RELAXED, __HIP_MEMORY_SCOPE_AGENT);
      *hb_word(hbA, bl, (1 - half) * 64 + p) = (uint32_t)wpA;
      while ((int)(wpB >> 32) < t + 1)
        wpB = __hip_atomic_load(ppB, __ATOMIC_RELAXED, __HIP_MEMORY_SCOPE_AGENT);
      *hb_word(hbB, bl, (1 - half) * 64 + p) = (uint32_t)wpB;
    }
    wg_barrier();  // BAR2 (no vmcnt drain)

#pragma unroll
    for (int j = 0; j < 4; ++j) { gvA[j] = gnA[j]; gvB[j] = gnB[j]; }
  }

  // chunk state (own half, both groups; partner WG writes its half)
  {
    size_t sbA = (size_t)bA * 256 + half * 128 + 2 * p;
    float2 hv; hv.x = hA0; hv.y = hA1;
    float2 cv; cv.x = cA0; cv.y = cA1;
    *(float2*)&hstate[sbA] = hv;
    *(float2*)&cstate[sbA] = cv;
    size_t sbB = (size_t)bB * 256 + half * 128 + 2 * p;
    float2 hw; hw.x = hB0; hw.y = hB1;
    float2 cw; cw.x = cB0; cw.y = cB1;
    *(float2*)&hstate[sbB] = hw;
    *(float2*)&cstate[sbB] = cw;
  }
}

// ---------------- orchestration ----------------

extern "C" void kernel_launch(void* const* d_in, const int* in_sizes, int n_in,
                              void* d_out, int out_size, void* d_ws, size_t ws_size,
                              hipStream_t stream) {
  const float* x = (const float*)d_in[0];
  const float* wih[3] = {(const float*)d_in[1], (const float*)d_in[5], (const float*)d_in[9]};
  const float* whh[3] = {(const float*)d_in[2], (const float*)d_in[6], (const float*)d_in[10]};
  const float* bi[3] = {(const float*)d_in[3], (const float*)d_in[7], (const float*)d_in[11]};
  const float* bh[3] = {(const float*)d_in[4], (const float*)d_in[8], (const float*)d_in[12]};
  float* y = (float*)d_out;

  // workspace layout (~155 MB total)
  char* p = (char*)d_ws;
  f16* Xf = (f16*)p;        p += (size_t)16777216 * 2;        // 33.5 MB
  f16* Wih0f = (f16*)p;     p += (size_t)131072 * 2;
  f16* Whh0f = (f16*)p;     p += (size_t)262144 * 2;
  f16* Wih1f = (f16*)p;     p += (size_t)262144 * 2;
  f16* Whh1f = (f16*)p;     p += (size_t)262144 * 2;
  f16* Wih2f = (f16*)p;     p += (size_t)262144 * 2;
  f16* Whh2f = (f16*)p;     p += (size_t)262144 * 2;
  float* bias0 = (float*)p; p += 4096;
  float* bias1 = (float*)p; p += 4096;
  float* bias2 = (float*)p; p += 4096;
  f16* Gbuf = (f16*)p;      p += (size_t)32768 * 1024 * 2;    // 67 MB chunk
  f16* H0e = (f16*)p;       p += (size_t)128 * 512 * 256 * 2; // 33.5 MB
  f16* H1q = (f16*)p;       p += (size_t)128 * 256 * 256 * 2; // 16.8 MB
  float* hstate = (float*)p; p += (size_t)128 * 256 * 4;
  float* cstate = (float*)p; p += (size_t)128 * 256 * 4;
  u64* hxw0 = (u64*)p;      p += (size_t)16 * 2 * 1024 * 8;   // 256 KB, tagged words
  u64* hxw1 = (u64*)p;      p += (size_t)16 * 2 * 1024 * 8;
  u64* hxw2 = (u64*)p;      p += (size_t)16 * 2 * 1024 * 8;

  // prep
  k_cvt_x<<<4096, 256, 0, stream>>>((const float2*)x, (v2h*)Xf, 8388608);
  k_prep_w<<<1024, 256, 0, stream>>>(wih[0], whh[0], wih[1], whh[1], wih[2], whh[2],
                                     bi[0], bh[0], bi[1], bh[1], bi[2], bh[2],
                                     Wih0f, Whh0f, Wih1f, Whh1f, Wih2f, Whh2f,
                                     bias0, bias1, bias2);

  // layer 0: 4 chunks of 256 steps
  for (int c = 0; c < 4; ++c) {
    k_gemm<128><<<512, 256, 0, stream>>>(Xf, 1024, c * 256, Wih0f, bias0, Gbuf);
    k_rec<0><<<16, 512, 0, stream>>>(Gbuf, Whh0f, c * 256, 256, H0e, nullptr,
                                     hstate, cstate, hxw0);
  }
  // layer 1: 2 chunks of 256 steps (inputs = h0 at even t)
  for (int c = 0; c < 2; ++c) {
    k_gemm<256><<<512, 256, 0, stream>>>(H0e, 512, c * 256, Wih1f, bias1, Gbuf);
    k_rec<1><<<16, 512, 0, stream>>>(Gbuf, Whh1f, c * 256, 256, H1q, nullptr,
                                     hstate, cstate, hxw1);
  }
  // layer 2: 1 chunk of 256 steps (inputs = h1 at t%4==0); writes y with 4x broadcast
  k_gemm<256><<<512, 256, 0, stream>>>(H1q, 256, 0, Wih2f, bias2, Gbuf);
  k_rec<2><<<16, 512, 0, stream>>>(Gbuf, Whh2f, 0, 256, nullptr, y,
                                   hstate, cstate, hxw2);
}

// Round 4
// 4679.189 us; speedup vs baseline: 1.5266x; 1.5266x over previous
//
#include <hip/hip_runtime.h>
#include <hip/hip_fp16.h>
#include <stdint.h>
#include <stddef.h>

// DRNN (dilated 3-layer LSTM), B=128, T=1024, F=128, H=256, dil=[1,2,4].
//  - Input GEMMs hoisted out of recurrence (f16 MFMA 16x16x32), G in 67MB chunks.
//  - R7 recurrence: R5/R6 were W_hh-bound (R5: 256KB/WG/step from L2 at the
//    per-CU L2 cap ~56B/cy = 1.9us/step; R6's asm-pin of 128 VGPRs caused
//    scratch spills, 2x worse). Fix: shrink W-per-wave until it is trivially
//    register-resident:
//      * 16 groups x 8 batches; each group split over 16 WGs, each WG owning
//        16 h-dims (64 gate cols). Grid 256 x 256 (1 WG/CU, full chip).
//        All 16 WGs of a group are == g (mod 8) -> same XCD under round-robin.
//      * Per wave (= 1 gate x 16 cols x K=256): B-frags = 8 v8h = 32 VGPR.
//        W read from L2 ONCE per kernel, zero restream.
//      * h in LDS [16][256] f16, 16B-chunk XOR swizzle (ch ^= row&7):
//        conflict-free MFMA A-frag ds_read_b128 + uint4 fill writes.
//      * Exchange: per-group shared buffer hx[g][tag&1][8 batch][128 words],
//        tagged words {tag=t+1 | f16x2}, relaxed agent atomics, parity
//        double-buffer. Each WG publishes its 64 words; every thread polls 4.
//        (Safety proof is participant-count independent; protocol verified
//        R3-R6.)
//      * Raw s_barrier + lgkmcnt(0) barriers (no vmcnt drain): G prefetch
//        stays in flight across barriers.

typedef _Float16 f16;
typedef _Float16 v2h __attribute__((ext_vector_type(2)));
typedef _Float16 v8h __attribute__((ext_vector_type(8)));
typedef __fp16 h2_raw __attribute__((ext_vector_type(2)));
typedef __fp16 h8_raw __attribute__((ext_vector_type(8)));
typedef float v4f __attribute__((ext_vector_type(4)));
typedef unsigned long long u64;

#define DEVINL static __device__ __forceinline__

DEVINL float sigm(float x) { return 1.0f / (1.0f + __expf(-x)); }
DEVINL float tanh_(float x) {
  x = fminf(fmaxf(x, -15.0f), 15.0f);
  float e = __expf(-2.0f * x);
  return (1.0f - e) / (1.0f + e);
}
DEVINL v2h pack2(float a, float b) {
  return __builtin_bit_cast(v2h, __builtin_amdgcn_cvt_pkrtz(a, b));
}
DEVINL v4f mfma_16x16x32(v8h a, v8h b, v4f c) {
  return __builtin_amdgcn_mfma_f32_16x16x32_f16(__builtin_bit_cast(h8_raw, a),
                                                __builtin_bit_cast(h8_raw, b), c,
                                                0, 0, 0);
}

// Workgroup barrier WITHOUT vmcnt drain: LDS ordered (lgkmcnt(0)), global
// loads/stores stay in flight (compiler inserts counted vmcnt at use).
DEVINL void wg_barrier() {
  __builtin_amdgcn_sched_barrier(0);
  asm volatile("s_waitcnt lgkmcnt(0)" ::: "memory");
  __builtin_amdgcn_s_barrier();
  asm volatile("" ::: "memory");
  __builtin_amdgcn_sched_barrier(0);
}

// ---------------- prep ----------------

__global__ void k_cvt_x(const float2* __restrict__ src, v2h* __restrict__ dst, int n2) {
  int i = blockIdx.x * blockDim.x + threadIdx.x;
  int st = gridDim.x * blockDim.x;
  for (; i < n2; i += st) {
    float2 v = src[i];
    dst[i] = pack2(v.x, v.y);
  }
}

__global__ void k_prep_w(const float* __restrict__ wih0, const float* __restrict__ whh0,
                         const float* __restrict__ wih1, const float* __restrict__ whh1,
                         const float* __restrict__ wih2, const float* __restrict__ whh2,
                         const float* __restrict__ bi0, const float* __restrict__ bh0,
                         const float* __restrict__ bi1, const float* __restrict__ bh1,
                         const float* __restrict__ bi2, const float* __restrict__ bh2,
                         f16* wih0f, f16* whh0f, f16* wih1f, f16* whh1f,
                         f16* wih2f, f16* whh2f,
                         float* bias0, float* bias1, float* bias2) {
  int i = blockIdx.x * blockDim.x + threadIdx.x;  // grid covers 262144
  if (i < 131072) wih0f[i] = (f16)wih0[i];
  whh0f[i] = (f16)whh0[i];
  wih1f[i] = (f16)wih1[i];
  whh1f[i] = (f16)whh1[i];
  wih2f[i] = (f16)wih2[i];
  whh2f[i] = (f16)whh2[i];
  if (i < 1024) {
    bias0[i] = bi0[i] + bh0[i];
    bias1[i] = bi1[i] + bh1[i];
    bias2[i] = bi2[i] + bh2[i];
  }
}

// ---------------- input GEMM (unchanged; measure next round) ----------------

template <int K>
__launch_bounds__(256)
__global__ void k_gemm(const f16* __restrict__ A, int Tb, int t0,
                       const f16* __restrict__ W, const float* __restrict__ bias,
                       f16* __restrict__ G) {
  constexpr int LDK = K + 8;
  __shared__ f16 As[64 * LDK];
  int b = blockIdx.x >> 2, tb = blockIdx.x & 3;
  const f16* Ablk = A + ((size_t)b * Tb + t0 + tb * 64) * K;
  int tid = threadIdx.x;

  constexpr int NV = 64 * K / 8;
  const uint4* src = (const uint4*)Ablk;
  for (int i = tid; i < NV; i += 256) {
    int e = i * 8;
    int r = e / K, c0 = e % K;
    *(uint4*)&As[r * LDK + c0] = src[i];
  }
  __syncthreads();

  int wave = tid >> 6, lane = tid & 63;
  int lm = lane & 15, lk = (lane >> 4) * 8;

  v8h af[K / 32];
#pragma unroll
  for (int kc = 0; kc < K / 32; ++kc)
    af[kc] = *(const v8h*)&As[(wave * 16 + lm) * LDK + kc * 32 + lk];

  size_t grow0 = (size_t)b * 256 + tb * 64 + wave * 16;
  for (int nt = 0; nt < 64; ++nt) {
    v4f acc = {0.0f, 0.0f, 0.0f, 0.0f};
    const f16* Wrow = W + (size_t)(nt * 16 + lm) * K + lk;
#pragma unroll
    for (int kc = 0; kc < K / 32; ++kc) {
      v8h bf = *(const v8h*)(Wrow + kc * 32);
      acc = mfma_16x16x32(af[kc], bf, acc);
    }
    float bv = bias[nt * 16 + lm];
#pragma unroll
    for (int r = 0; r < 4; ++r) {
      int m = (lane >> 4) * 4 + r;
      G[(grow0 + m) * 1024 + nt * 16 + lm] = (f16)(acc[r] + bv);
    }
  }
}

// ---------------- recurrence (R7: 16-way col-split, resident W) ----------------
// grid 256 x 256. g = blk & 15 (batches [g*8, g*8+8)), sub = blk >> 4,
// d0 = sub*16 (h-dims [d0, d0+16), gate cols {q*256+d0..+15, q=0..3}).
// Wave wv = gate q. B-frags wf[8] (32 VGPR). K=256 = 8 K-tiles, 8 MFMA/wave.
// Cell: lanes 0..15 of each wave -> (batch 2*wv + (lane>>3), word wp=lane&7),
//   i.e. dims d0+2wp, d0+2wp+1. 64 cell threads per WG.
// Poll: thread tid polls words flat = tid*4..+3 of [8 batch][128 words],
//   writes hbuf via one swizzled uint4 ds_write.
// Per step: P1 {8 MFMA, gq stores, G prefetch} BAR1
//           P2 {cell, publish, outputs, poll 4 words, hbuf fill} BAR2.

template <int LAYER>
__launch_bounds__(256)
__global__ void k_rec(const f16* __restrict__ G,   // chunk [128][256][1024] f16
                      const f16* __restrict__ Whh, // [1024][256] f16
                      int t0, int steps,
                      f16* __restrict__ Hout, float* __restrict__ y,
                      float* __restrict__ hstate, float* __restrict__ cstate,
                      u64* hxw) {
  int blk = blockIdx.x;                 // 0..255
  int g = blk & 15, sub = blk >> 4;     // all WGs of group g: same XCD (mod 8)
  int d0 = sub * 16;
  int tid = threadIdx.x;
  int lane = tid & 63, wv = tid >> 6;
  int q = wv;                            // gate
  int arow = lane & 15, s4 = lane >> 4;  // MFMA A-row / k-subgroup

  // cell role: lanes 0..15 -> (bl, wp)
  bool is_cell = (lane < 16);
  int bl = 2 * wv + (lane >> 3);         // valid when is_cell
  int wp = lane & 7;
  int b = g * 8 + bl;

  // poll role: thread covers words flat = tid*4..+3 => row pbl, words pwd..+3
  int pbl = tid >> 5;
  int pwd = (tid & 31) * 4;

  __shared__ __align__(16) f16 hbuf[16][256];  // swizzled, rows 8-15 zero
  __shared__ float gq[4][8][18];               // [gate][batch][dim], pad 2

  // W_hh B-frags: wf[kt], lane holds Whh[q*256+d0+arow][kt*32 + s4*8 + j]
  v8h wf[8];
  {
    const v8h* wrow = (const v8h*)&Whh[(size_t)(q * 256 + d0 + arow) * 256];
#pragma unroll
    for (int kt = 0; kt < 8; ++kt) wf[kt] = wrow[kt * 4 + s4];
#pragma unroll
    for (int i = 0; i < 8; ++i)
      asm volatile("" : "+v"(wf[i]));  // keep resident (low pressure: safe)
  }

  // swizzled hbuf pointers for this thread's fill row / zero row
  char* fillp = (char*)hbuf + pbl * 512 + (((tid & 31) ^ (pbl & 7)) * 16);
  char* fillz = (char*)hbuf + (8 + pbl) * 512 + (((tid & 31) ^ (pbl & 7)) * 16);

  float c0 = 0.f, c1 = 0.f, h0 = 0.f, h1 = 0.f;
  {
    uint4 z = {0u, 0u, 0u, 0u};
    *(uint4*)fillz = z;  // rows 8-15: permanent zeros (MFMA M-padding)
    if (t0 == 0) {
      *(uint4*)fillp = z;
    } else {  // restore h into hbuf, own c into regs
      int bq = g * 8 + pbl;
      const float4* hs = (const float4*)&hstate[(size_t)bq * 256 + 2 * pwd];
      float4 u = hs[0], v = hs[1];
      uint4 pk;
      pk.x = __builtin_bit_cast(uint32_t, pack2(u.x, u.y));
      pk.y = __builtin_bit_cast(uint32_t, pack2(u.z, u.w));
      pk.z = __builtin_bit_cast(uint32_t, pack2(v.x, v.y));
      pk.w = __builtin_bit_cast(uint32_t, pack2(v.z, v.w));
      *(uint4*)fillp = pk;
      if (is_cell) {
        float2 cc = *(const float2*)&cstate[(size_t)b * 256 + d0 + 2 * wp];
        c0 = cc.x; c1 = cc.y;
      }
    }
  }
  __syncthreads();

  u64* hx_g = hxw + (size_t)g * 2048;                     // [2][8][128] u64
  u64* pubp = hx_g + (size_t)bl * 128 + (d0 >> 1) + wp;   // + pp*1024
  const u64* pollp = hx_g + (size_t)pbl * 128 + pwd;      // + pp*1024

  const f16* Gc = G + (size_t)b * 262144 + d0 + 2 * wp;   // cell threads only
  uint32_t gv[4] = {0, 0, 0, 0}, gn[4] = {0, 0, 0, 0};
  if (is_cell) {
#pragma unroll
    for (int j = 0; j < 4; ++j) gv[j] = *(const uint32_t*)&Gc[j * 256];
  }

  for (int s = 0; s < steps; ++s) {
    int t = t0 + s;
    int pp = (t + 1) & 1;  // publish/poll parity for tag t+1

    // ---- P1: MFMA h x W_hh^T (A from swizzled LDS, B resident) ----
    v4f acc0 = {0.f, 0.f, 0.f, 0.f}, acc1 = {0.f, 0.f, 0.f, 0.f};
#pragma unroll
    for (int kt = 0; kt < 8; kt += 2) {
      v8h a0 = *(const v8h*)((const char*)hbuf + arow * 512 +
                             (((kt * 4 + s4) ^ (arow & 7)) * 16));
      acc0 = mfma_16x16x32(a0, wf[kt], acc0);
      v8h a1 = *(const v8h*)((const char*)hbuf + arow * 512 +
                             ((((kt + 1) * 4 + s4) ^ (arow & 7)) * 16));
      acc1 = mfma_16x16x32(a1, wf[kt + 1], acc1);
    }
    if (lane < 32) {  // D: batch=(lane>>4)*4+r (valid 0..7), dim=arow
      int r0 = s4 * 4;
#pragma unroll
      for (int r = 0; r < 4; ++r) gq[q][r0 + r][arow] = acc0[r] + acc1[r];
    }
    // G prefetch for t+1 (stays in flight across the raw barriers)
    if (is_cell && s + 1 < steps) {
#pragma unroll
      for (int j = 0; j < 4; ++j)
        gn[j] = *(const uint32_t*)&Gc[(size_t)(s + 1) * 1024 + j * 256];
    }
    wg_barrier();  // BAR1 (no vmcnt drain)

    // ---- P2: cell + publish + poll/fill ----
    if (is_cell) {
      float2 zi = *(const float2*)&gq[0][bl][2 * wp];
      float2 zf = *(const float2*)&gq[1][bl][2 * wp];
      float2 zg = *(const float2*)&gq[2][bl][2 * wp];
      float2 zo = *(const float2*)&gq[3][bl][2 * wp];
      v2h G0 = __builtin_bit_cast(v2h, gv[0]);
      v2h G1 = __builtin_bit_cast(v2h, gv[1]);
      v2h G2 = __builtin_bit_cast(v2h, gv[2]);
      v2h G3 = __builtin_bit_cast(v2h, gv[3]);
      float i0 = sigm(zi.x + (float)G0[0]), i1 = sigm(zi.y + (float)G0[1]);
      float f0 = sigm(zf.x + (float)G1[0]), f1 = sigm(zf.y + (float)G1[1]);
      float g0 = tanh_(zg.x + (float)G2[0]), g1 = tanh_(zg.y + (float)G2[1]);
      float o0 = sigm(zo.x + (float)G3[0]), o1 = sigm(zo.y + (float)G3[1]);
      c0 = f0 * c0 + i0 * g0;
      c1 = f1 * c1 + i1 * g1;
      h0 = o0 * tanh_(c0);
      h1 = o1 * tanh_(c1);

      uint32_t hp = __builtin_bit_cast(uint32_t, pack2(h0, h1));
      __hip_atomic_store(pubp + (size_t)pp * 1024,  // publish FIRST
                         ((u64)(uint32_t)(t + 1) << 32) | (u64)hp,
                         __ATOMIC_RELAXED, __HIP_MEMORY_SCOPE_AGENT);

      // outputs (fire-and-forget)
      if (LAYER == 0) {
        if ((t & 1) == 0) {
          v2h hr; hr[0] = (f16)h0; hr[1] = (f16)h1;
          *(uint32_t*)&Hout[((size_t)b * 512 + (t >> 1)) * 256 + d0 + 2 * wp] =
              __builtin_bit_cast(uint32_t, hr);
        }
      } else if (LAYER == 1) {
        if ((t & 1) == 0) {
          v2h hr; hr[0] = (f16)h0; hr[1] = (f16)h1;
          *(uint32_t*)&Hout[((size_t)b * 256 + (t >> 1)) * 256 + d0 + 2 * wp] =
              __builtin_bit_cast(uint32_t, hr);
        }
      } else {
        size_t base = ((size_t)b * 1024 + (size_t)t * 4) * 256 + d0 + 2 * wp;
        float2 hv; hv.x = h0; hv.y = h1;
        *(float2*)&y[base] = hv;
        *(float2*)&y[base + 256] = hv;
        *(float2*)&y[base + 512] = hv;
        *(float2*)&y[base + 768] = hv;
      }
    }

    if (s + 1 < steps) {  // gather full h_{t+1} for next step's MFMA
      const u64* pb = pollp + (size_t)pp * 1024;
      int tau = t + 1;
      u64 w0, w1, w2, w3;
      for (;;) {
        w0 = __hip_atomic_load(pb + 0, __ATOMIC_RELAXED, __HIP_MEMORY_SCOPE_AGENT);
        w1 = __hip_atomic_load(pb + 1, __ATOMIC_RELAXED, __HIP_MEMORY_SCOPE_AGENT);
        w2 = __hip_atomic_load(pb + 2, __ATOMIC_RELAXED, __HIP_MEMORY_SCOPE_AGENT);
        w3 = __hip_atomic_load(pb + 3, __ATOMIC_RELAXED, __HIP_MEMORY_SCOPE_AGENT);
        if ((int)(w0 >> 32) >= tau && (int)(w1 >> 32) >= tau &&
            (int)(w2 >> 32) >= tau && (int)(w3 >> 32) >= tau)
          break;
      }
      uint4 pk;
      pk.x = (uint32_t)w0; pk.y = (uint32_t)w1;
      pk.z = (uint32_t)w2; pk.w = (uint32_t)w3;
      *(uint4*)fillp = pk;
    }
    wg_barrier();  // BAR2 (no vmcnt drain)

    if (is_cell) {
#pragma unroll
      for (int j = 0; j < 4; ++j) gv[j] = gn[j];
    }
  }

  if (is_cell) {  // chunk state for own dims (all subs cover all 256 dims)
    size_t sb = (size_t)b * 256 + d0 + 2 * wp;
    float2 hv; hv.x = h0; hv.y = h1;
    float2 cv; cv.x = c0; cv.y = c1;
    *(float2*)&hstate[sb] = hv;
    *(float2*)&cstate[sb] = cv;
  }
}

// ---------------- orchestration ----------------

extern "C" void kernel_launch(void* const* d_in, const int* in_sizes, int n_in,
                              void* d_out, int out_size, void* d_ws, size_t ws_size,
                              hipStream_t stream) {
  const float* x = (const float*)d_in[0];
  const float* wih[3] = {(const float*)d_in[1], (const float*)d_in[5], (const float*)d_in[9]};
  const float* whh[3] = {(const float*)d_in[2], (const float*)d_in[6], (const float*)d_in[10]};
  const float* bi[3] = {(const float*)d_in[3], (const float*)d_in[7], (const float*)d_in[11]};
  const float* bh[3] = {(const float*)d_in[4], (const float*)d_in[8], (const float*)d_in[12]};
  float* y = (float*)d_out;

  // workspace layout (~155 MB total)
  char* p = (char*)d_ws;
  f16* Xf = (f16*)p;        p += (size_t)16777216 * 2;        // 33.5 MB
  f16* Wih0f = (f16*)p;     p += (size_t)131072 * 2;
  f16* Whh0f = (f16*)p;     p += (size_t)262144 * 2;
  f16* Wih1f = (f16*)p;     p += (size_t)262144 * 2;
  f16* Whh1f = (f16*)p;     p += (size_t)262144 * 2;
  f16* Wih2f = (f16*)p;     p += (size_t)262144 * 2;
  f16* Whh2f = (f16*)p;     p += (size_t)262144 * 2;
  float* bias0 = (float*)p; p += 4096;
  float* bias1 = (float*)p; p += 4096;
  float* bias2 = (float*)p; p += 4096;
  f16* Gbuf = (f16*)p;      p += (size_t)32768 * 1024 * 2;    // 67 MB chunk
  f16* H0e = (f16*)p;       p += (size_t)128 * 512 * 256 * 2; // 33.5 MB
  f16* H1q = (f16*)p;       p += (size_t)128 * 256 * 256 * 2; // 16.8 MB
  float* hstate = (float*)p; p += (size_t)128 * 256 * 4;
  float* cstate = (float*)p; p += (size_t)128 * 256 * 4;
  u64* hxw0 = (u64*)p;      p += (size_t)16 * 2 * 1024 * 8;   // 256 KB tagged words
  u64* hxw1 = (u64*)p;      p += (size_t)16 * 2 * 1024 * 8;
  u64* hxw2 = (u64*)p;      p += (size_t)16 * 2 * 1024 * 8;

  // prep
  k_cvt_x<<<4096, 256, 0, stream>>>((const float2*)x, (v2h*)Xf, 8388608);
  k_prep_w<<<1024, 256, 0, stream>>>(wih[0], whh[0], wih[1], whh[1], wih[2], whh[2],
                                     bi[0], bh[0], bi[1], bh[1], bi[2], bh[2],
                                     Wih0f, Whh0f, Wih1f, Whh1f, Wih2f, Whh2f,
                                     bias0, bias1, bias2);

  // layer 0: 4 chunks of 256 steps
  for (int c = 0; c < 4; ++c) {
    k_gemm<128><<<512, 256, 0, stream>>>(Xf, 1024, c * 256, Wih0f, bias0, Gbuf);
    k_rec<0><<<256, 256, 0, stream>>>(Gbuf, Whh0f, c * 256, 256, H0e, nullptr,
                                      hstate, cstate, hxw0);
  }
  // layer 1: 2 chunks of 256 steps (inputs = h0 at even t)
  for (int c = 0; c < 2; ++c) {
    k_gemm<256><<<512, 256, 0, stream>>>(H0e, 512, c * 256, Wih1f, bias1, Gbuf);
    k_rec<1><<<256, 256, 0, stream>>>(Gbuf, Whh1f, c * 256, 256, H1q, nullptr,
                                      hstate, cstate, hxw1);
  }
  // layer 2: 1 chunk of 256 steps (inputs = h1 at t%4==0); writes y with 4x broadcast
  k_gemm<256><<<512, 256, 0, stream>>>(H1q, 256, 0, Wih2f, bias2, Gbuf);
  k_rec<2><<<256, 256, 0, stream>>>(Gbuf, Whh2f, 0, 256, nullptr, y,
                                    hstate, cstate, hxw2);
}